// Round 1
// baseline (195.338 us; speedup 1.0000x reference)
//
#include <hip/hip_runtime.h>

#define NB   2048
#define SEQ  200
#define DIM  64
#define NH1  64
#define NH2  16
#define EPSF 1e-9f

typedef float fvec4 __attribute__((ext_vector_type(4)));
typedef short svec8 __attribute__((ext_vector_type(8)));   // 8 bf16 = 4 VGPRs

// LDS layout (bytes)
#define WCB_OFF   0        // 8192 B : Wc B-frags, bf16, frag layout
#define H1F_OFF   8192     // 8192 B : per-wave h1 A-frags (4 waves x 2 KB)
#define QPART_OFF 16384    // 1024 B : qterm partials (setup); aliased by outp
#define QALL_OFF  17408    // 256 B  : qterm[64]
#define SMEM_BYTES 17664

__device__ __forceinline__ short f2bf(float f) {
    unsigned u = __float_as_uint(f);
    u += 0x7fffu + ((u >> 16) & 1u);      // round-to-nearest-even
    return (short)(u >> 16);
}

__global__ __launch_bounds__(256, 4)
void din_attn_kernel(const float* __restrict__ q,        // [B,64]
                     const float* __restrict__ key,      // [B,200,64]
                     const int*   __restrict__ seqlen,   // [B,1]
                     const float* __restrict__ W1,       // [256,64]
                     const float* __restrict__ alpha1v,
                     const float* __restrict__ mean1v,
                     const float* __restrict__ var1v,
                     const float* __restrict__ W2,       // [64,16]
                     const float* __restrict__ alpha2v,
                     const float* __restrict__ mean2v,
                     const float* __restrict__ var2v,
                     const float* __restrict__ W3,       // [16]
                     float* __restrict__ out)            // [B,64]
{
    __shared__ __align__(16) char smem[SMEM_BYTES];
    char*  wcb   = smem + WCB_OFF;
    char*  h1f   = smem + H1F_OFF;
    float* qpart = (float*)(smem + QPART_OFF);
    float* qall  = (float*)(smem + QALL_OFF);
    float* outp  = (float*)(smem + QPART_OFF);   // epilogue alias (safe: qpart
                                                 // last read before barrier 2)

    const int b    = blockIdx.x;
    const int t    = threadIdx.x;
    const int lane = t & 63;
    const int wave = __builtin_amdgcn_readfirstlane(t >> 6);
    const int qd4  = lane >> 4;     // quad 0..3
    const int m    = lane & 15;

    const float* qrow = q + (size_t)b * DIM;
    int nseq = seqlen[b];
    nseq = nseq < SEQ ? nseq : SEQ;

    // ---- setup 1: Wc = (W1b - W1c) + q[d]*W1d, written as bf16 directly in
    //      B-frag layout; qterm partials.  Frag for element (d,h):
    //      frag=(h>>4)*2+(d>>5), lane'=((d>>3)&3)*16+(h&15), byte j=(d&7)*2.
    {
        const int h  = lane;
        const int c  = h >> 4;
        const int mm = h & 15;
        float qt = 0.f;
        #pragma unroll
        for (int i = 0; i < 16; ++i) {
            const int d = wave * 16 + i;
            const float qdv  = qrow[d];
            const float w1a  = W1[(d)       * NH1 + h];
            const float w1b  = W1[(64 + d)  * NH1 + h];
            const float w1c  = W1[(128 + d) * NH1 + h];
            const float w1dd = W1[(192 + d) * NH1 + h];
            const float wc   = (w1b - w1c) + qdv * w1dd;
            qt = fmaf(qdv, w1a + w1c, qt);
            const int frag = (c << 1) | (d >> 5);
            const int ln   = (((d >> 3) & 3) << 4) | mm;
            *(short*)(wcb + (frag << 10) + (ln << 4) + ((d & 7) << 1)) = f2bf(wc);
        }
        qpart[wave * 64 + h] = qt;
    }
    __syncthreads();

    // ---- setup 2: qterm reduce (wave 0); everyone builds frags/params
    if (t < 64)
        qall[t] = (qpart[t] + qpart[64 + t]) + (qpart[128 + t] + qpart[192 + t]);

    svec8 wcf[4][2];   // Wc B-frags, now vector loads from frag-layout LDS
    #pragma unroll
    for (int c = 0; c < 4; ++c)
        #pragma unroll
        for (int kk = 0; kk < 2; ++kk)
            wcf[c][kk] = *(const svec8*)(wcb + (((c << 1) | kk) << 10) + (lane << 4));

    svec8 w2f[2];      // W2 B-frags (tiny, L2-hot)
    #pragma unroll
    for (int kk = 0; kk < 2; ++kk) {
        svec8 f;
        #pragma unroll
        for (int j = 0; j < 8; ++j) {
            const int h = kk * 32 + qd4 * 8 + j;
            f[j] = f2bf(W2[h * NH2 + m]);
        }
        w2f[kk] = f;
    }

    // dice1 params for h = c*16 + m
    float a1p[4], m1p[4], r1p[4];
    #pragma unroll
    for (int c = 0; c < 4; ++c) {
        a1p[c] = alpha1v[c * 16 + m];
        m1p[c] = mean1v[c * 16 + m];
        r1p[c] = rsqrtf(var1v[c * 16 + m] + EPSF);
    }
    // dice2 params for j = m
    const float a2s = alpha2v[m];
    const float m2s = mean2v[m];
    const float r2s = rsqrtf(var2v[m] + EPSF);
    const float w3s = W3[m];

    __syncthreads();   // qall ready; wcb read-only from here

    float qtermv[4];
    #pragma unroll
    for (int c = 0; c < 4; ++c) qtermv[c] = qall[c * 16 + m];

    char* myh1 = h1f + (wave << 11);   // 2 KB private transpose buffer
    float oacc = 0.f;                  // lane = d output partial

    // ---- barrier-free main loop: wave owns rows [rb, rb+16), rb += 64.
    //      Early exit per wave when its row-block start passes nseq.
    for (int rb = wave * 16; rb < nseq; rb += 64) {
        // A-frags straight from global: lane 16q+m holds k[rb+m][q*8+j(+32)]
        int rm = rb + m;
        rm = rm < SEQ ? rm : SEQ - 1;              // garbage rows weight 0
        const float* arow = key + ((size_t)b * SEQ + rm) * DIM + (qd4 << 3);
        const fvec4 f0 = *(const fvec4*)(arow);
        const fvec4 f1 = *(const fvec4*)(arow + 4);
        const fvec4 f2 = *(const fvec4*)(arow + 32);
        const fvec4 f3 = *(const fvec4*)(arow + 36);
        svec8 a0, a1;
        #pragma unroll
        for (int jj = 0; jj < 4; ++jj) {
            a0[jj]     = f2bf(f0[jj]);
            a0[jj + 4] = f2bf(f1[jj]);
            a1[jj]     = f2bf(f2[jj]);
            a1[jj + 4] = f2bf(f3[jj]);
        }

        // ---- phase 1: x = k @ Wc + qterm (qterm folded into acc init)
        fvec4 acc[4];
        #pragma unroll
        for (int c = 0; c < 4; ++c) {
            fvec4 a = (fvec4){qtermv[c], qtermv[c], qtermv[c], qtermv[c]};
            a = __builtin_amdgcn_mfma_f32_16x16x32_bf16(a0, wcf[c][0], a, 0, 0, 0);
            a = __builtin_amdgcn_mfma_f32_16x16x32_bf16(a1, wcf[c][1], a, 0, 0, 0);
            acc[c] = a;
        }

        // ---- dice1; write h1 (bf16) into per-wave phase-2 A-frag buffer
        #pragma unroll
        for (int c = 0; c < 4; ++c) {
            const int kk2 = c >> 1;
            const int qhi = (c & 1) * 2 + (m >> 3);
            #pragma unroll
            for (int reg = 0; reg < 4; ++reg) {
                const float x  = acc[c][reg];
                const float xn = (x - m1p[c]) * r1p[c];
                const float p  = 1.f / (1.f + __expf(-xn));
                const float h1 = x * (a1p[c] + p * (1.f - a1p[c]));
                const int l2 = (qhi << 4) | ((qd4 << 2) | reg);
                *(short*)(myh1 + (kk2 << 10) + (l2 << 4) + ((m & 7) << 1))
                    = f2bf(h1);
            }
        }
        // same-wave write->read; compiler inserts lgkmcnt, no barrier

        // ---- phase 2: h2 = h1 @ W2; dice2; score
        const svec8 b0 = *(const svec8*)(myh1 + (lane << 4));
        const svec8 b1 = *(const svec8*)(myh1 + 1024 + (lane << 4));
        fvec4 acc2 = (fvec4){0.f, 0.f, 0.f, 0.f};
        acc2 = __builtin_amdgcn_mfma_f32_16x16x32_bf16(b0, w2f[0], acc2, 0, 0, 0);
        acc2 = __builtin_amdgcn_mfma_f32_16x16x32_bf16(b1, w2f[1], acc2, 0, 0, 0);

        float wv[4];   // sigmoid scores for rows rb + qd4*4 + reg
        #pragma unroll
        for (int reg = 0; reg < 4; ++reg) {
            const float x  = acc2[reg];
            const float xn = (x - m2s) * r2s;
            const float p  = 1.f / (1.f + __expf(-xn));
            const float hd = x * (a2s + p * (1.f - a2s));
            float s = hd * w3s;                         // partial over j = m
            s += __shfl_xor(s, 1);
            s += __shfl_xor(s, 2);
            s += __shfl_xor(s, 4);
            s += __shfl_xor(s, 8);                      // all 16 j-lanes summed
            const int r = rb + (qd4 << 2) + reg;
            wv[reg] = (r < nseq) ? 1.f / (1.f + __expf(-s)) : 0.f;
        }

        // ---- phase 3: oacc[d=lane] += w[i] * k[rb+i][d]; weights via
        //      constant-lane shfl (readlane -> SGPR), rows L1-hot
        const float* kbase = key + ((size_t)b * SEQ + rb) * DIM + lane;
        #pragma unroll
        for (int i = 0; i < 16; ++i) {
            if (rb + i >= nseq) break;                  // wave-uniform
            const float w = __shfl(wv[i & 3], (i >> 2) << 4);
            oacc = fmaf(w, kbase[i * DIM], oacc);
        }
    }

    // ---- cross-wave output reduction (only barrier after setup)
    outp[wave * 64 + lane] = oacc;
    __syncthreads();
    if (t < 64) {
        out[(size_t)b * DIM + t] = (outp[t] + outp[64 + t]) +
                                   (outp[128 + t] + outp[192 + t]);
    }
}

extern "C" void kernel_launch(void* const* d_in, const int* in_sizes, int n_in,
                              void* d_out, int out_size, void* d_ws, size_t ws_size,
                              hipStream_t stream) {
    const float* q      = (const float*)d_in[0];
    const float* key    = (const float*)d_in[1];
    const int*   seqlen = (const int*)d_in[2];
    const float* W1     = (const float*)d_in[3];
    const float* alpha1 = (const float*)d_in[4];
    const float* mean1  = (const float*)d_in[5];
    const float* var1   = (const float*)d_in[6];
    const float* W2     = (const float*)d_in[7];
    const float* alpha2 = (const float*)d_in[8];
    const float* mean2  = (const float*)d_in[9];
    const float* var2   = (const float*)d_in[10];
    const float* W3     = (const float*)d_in[11];
    float* out          = (float*)d_out;

    din_attn_kernel<<<NB, 256, 0, stream>>>(q, key, seqlen, W1,
                                            alpha1, mean1, var1,
                                            W2, alpha2, mean2, var2,
                                            W3, out);
}

// Round 2
// 179.436 us; speedup vs baseline: 1.0886x; 1.0886x over previous
//
#include <hip/hip_runtime.h>

#define NB   2048
#define SEQ  200
#define DIM  64
#define NH1  64
#define NH2  16
#define EPSF 1e-9f

typedef float fvec4 __attribute__((ext_vector_type(4)));
typedef short svec8 __attribute__((ext_vector_type(8)));   // 8 bf16 = 4 VGPRs

// LDS layout (bytes). h1 transpose buffers alias the setup-only Wc frag
// region (fenced by the second __syncthreads).
#define WCB_OFF   0        // 8192 B : setup Wc B-frags / main-loop h1f (4 x 2KB)
#define QPART_OFF 8192     // 1024 B : qterm partials (setup) / outp (epilogue)
#define QALL_OFF  9216     // 256 B  : qterm[64]
#define SMEM_BYTES 9472

__device__ __forceinline__ short f2bf(float f) {
    unsigned u = __float_as_uint(f);
    u += 0x7fffu + ((u >> 16) & 1u);      // round-to-nearest-even
    return (short)(u >> 16);
}

__global__ __launch_bounds__(256, 3)
void din_attn_kernel(const float* __restrict__ q,        // [B,64]
                     const float* __restrict__ key,      // [B,200,64]
                     const int*   __restrict__ seqlen,   // [B,1]
                     const float* __restrict__ W1,       // [256,64]
                     const float* __restrict__ alpha1v,
                     const float* __restrict__ mean1v,
                     const float* __restrict__ var1v,
                     const float* __restrict__ W2,       // [64,16]
                     const float* __restrict__ alpha2v,
                     const float* __restrict__ mean2v,
                     const float* __restrict__ var2v,
                     const float* __restrict__ W3,       // [16]
                     float* __restrict__ out)            // [B,64]
{
    __shared__ __align__(16) char smem[SMEM_BYTES];
    char*  wcb   = smem + WCB_OFF;                 // setup Wc frags
    char*  h1f   = smem + WCB_OFF;                 // main-loop alias
    float* qpart = (float*)(smem + QPART_OFF);
    float* qall  = (float*)(smem + QALL_OFF);
    float* outp  = (float*)(smem + QPART_OFF);     // epilogue alias

    const int b    = blockIdx.x;
    const int t    = threadIdx.x;
    const int lane = t & 63;
    const int wave = __builtin_amdgcn_readfirstlane(t >> 6);
    const int qd4  = lane >> 4;     // quad 0..3
    const int m    = lane & 15;

    const float* qrow = q + (size_t)b * DIM;
    int nseq = seqlen[b];
    nseq = nseq < SEQ ? nseq : SEQ;

    // ---- setup 1: Wc = (W1b - W1c) + q[d]*W1d written as bf16 in frag
    //      layout; qterm partials.  Element (d,h) -> frag=(h>>4)*2+(d>>5),
    //      slot=((d>>3)&3)*16+(h&15), byte j=(d&7)*2.
    {
        const int h  = lane;
        const int c  = h >> 4;
        const int mm = h & 15;
        float qt = 0.f;
        #pragma unroll
        for (int i = 0; i < 16; ++i) {
            const int d = wave * 16 + i;
            const float qdv  = qrow[d];
            const float w1a  = W1[(d)       * NH1 + h];
            const float w1b  = W1[(64 + d)  * NH1 + h];
            const float w1c  = W1[(128 + d) * NH1 + h];
            const float w1dd = W1[(192 + d) * NH1 + h];
            const float wc   = (w1b - w1c) + qdv * w1dd;
            qt = fmaf(qdv, w1a + w1c, qt);
            const int frag = (c << 1) | (d >> 5);
            const int ln   = (((d >> 3) & 3) << 4) | mm;
            *(short*)(wcb + (frag << 10) + (ln << 4) + ((d & 7) << 1)) = f2bf(wc);
        }
        qpart[wave * 64 + h] = qt;
    }
    __syncthreads();

    // ---- setup 2: qterm reduce; frags to registers; params
    if (t < 64)
        qall[t] = (qpart[t] + qpart[64 + t]) + (qpart[128 + t] + qpart[192 + t]);

    svec8 wcf[4][2];   // Wc B-frags (phase-1 B operand)
    #pragma unroll
    for (int c = 0; c < 4; ++c)
        #pragma unroll
        for (int kk = 0; kk < 2; ++kk)
            wcf[c][kk] = *(const svec8*)(wcb + (((c << 1) | kk) << 10) + (lane << 4));

    // W2 frags. Same values as before but consumed as the *A* operand of a
    // transposed phase-2: A[row=j=m][k=h=kk*32+qd4*8+jj] = W2[h][j].
    svec8 w2f[2];
    #pragma unroll
    for (int kk = 0; kk < 2; ++kk) {
        svec8 f;
        #pragma unroll
        for (int j = 0; j < 8; ++j) {
            const int h = kk * 32 + qd4 * 8 + j;
            f[j] = f2bf(W2[h * NH2 + m]);
        }
        w2f[kk] = f;
    }

    // dice1 params for h = c*16 + m (phase-1 output cols unchanged)
    float a1p[4], m1p[4], r1p[4];
    #pragma unroll
    for (int c = 0; c < 4; ++c) {
        a1p[c] = alpha1v[c * 16 + m];
        m1p[c] = mean1v[c * 16 + m];
        r1p[c] = rsqrtf(var1v[c * 16 + m] + EPSF);
    }
    // dice2 params for j = qd4*4 + reg (transposed phase-2 output rows)
    float a2p[4], m2p[4], r2p[4], w3p[4];
    #pragma unroll
    for (int reg = 0; reg < 4; ++reg) {
        const int j = qd4 * 4 + reg;
        a2p[reg] = alpha2v[j];
        m2p[reg] = mean2v[j];
        r2p[reg] = rsqrtf(var2v[j] + EPSF);
        w3p[reg] = W3[j];
    }

    __syncthreads();   // wcb reads done -> h1f alias safe; qall ready

    float qtermv[4];
    #pragma unroll
    for (int c = 0; c < 4; ++c) qtermv[c] = qall[c * 16 + m];

    char* myh1 = h1f + (wave << 11);   // 2 KB private transpose buffer
    const float* kb = key + (size_t)b * (SEQ * DIM);

    fvec4 oa0 = (fvec4){0.f,0.f,0.f,0.f};   // out cols qd4*8+0..3
    fvec4 oa1 = (fvec4){0.f,0.f,0.f,0.f};   // out cols qd4*8+4..7
    fvec4 oa2 = (fvec4){0.f,0.f,0.f,0.f};   // out cols 32+qd4*8+0..3
    fvec4 oa3 = (fvec4){0.f,0.f,0.f,0.f};   // out cols 32+qd4*8+4..7

    // ---- barrier-free main loop: wave owns rows [rb, rb+16), rb += 64
    for (int rb = wave * 16; rb < nseq; rb += 64) {
        int rm = rb + m;
        rm = rm < SEQ ? rm : SEQ - 1;              // garbage rows -> w=0
        const float* arow = kb + rm * DIM + (qd4 << 3);
        const fvec4 f0 = *(const fvec4*)(arow);
        const fvec4 f1 = *(const fvec4*)(arow + 4);
        const fvec4 f2 = *(const fvec4*)(arow + 32);
        const fvec4 f3 = *(const fvec4*)(arow + 36);
        svec8 a0, a1;
        #pragma unroll
        for (int jj = 0; jj < 4; ++jj) {
            a0[jj]     = f2bf(f0[jj]);
            a0[jj + 4] = f2bf(f1[jj]);
            a1[jj]     = f2bf(f2[jj]);
            a1[jj + 4] = f2bf(f3[jj]);
        }

        // ---- phase 1: x = k @ Wc + qterm (qterm in acc init)
        fvec4 acc[4];
        #pragma unroll
        for (int c = 0; c < 4; ++c) {
            fvec4 a = (fvec4){qtermv[c], qtermv[c], qtermv[c], qtermv[c]};
            a = __builtin_amdgcn_mfma_f32_16x16x32_bf16(a0, wcf[c][0], a, 0, 0, 0);
            a = __builtin_amdgcn_mfma_f32_16x16x32_bf16(a1, wcf[c][1], a, 0, 0, 0);
            acc[c] = a;
        }

        // ---- dice1; h1 -> LDS in frag layout, XOR-swizzled slots
        //      (write conflict drops 8-way -> 2-way; read is same involution)
        #pragma unroll
        for (int c = 0; c < 4; ++c) {
            const int kk2 = c >> 1;
            const int qhi = (c & 1) * 2 + (m >> 3);
            #pragma unroll
            for (int reg = 0; reg < 4; ++reg) {
                const float x  = acc[c][reg];
                const float xn = (x - m1p[c]) * r1p[c];
                const float p  = 1.f / (1.f + __expf(-xn));
                const float h1 = x * (a1p[c] + p * (1.f - a1p[c]));
                const int l2  = (qhi << 4) | ((qd4 << 2) | reg);
                const int l2s = l2 ^ ((l2 >> 3) & 7);
                *(short*)(myh1 + (kk2 << 10) + (l2s << 4) + ((m & 7) << 1))
                    = f2bf(h1);
            }
        }
        // same-wave write->read; compiler inserts lgkmcnt, no barrier

        // ---- phase 2 (operand-swapped): h2^T = W2^T @ h1^T
        //      C[row=j=qd4*4+reg][col=seqrow=m]
        const int slot = lane ^ ((lane >> 3) & 7);
        const svec8 b0 = *(const svec8*)(myh1 + (slot << 4));
        const svec8 b1 = *(const svec8*)(myh1 + 1024 + (slot << 4));
        fvec4 acc2 = (fvec4){0.f, 0.f, 0.f, 0.f};
        acc2 = __builtin_amdgcn_mfma_f32_16x16x32_bf16(w2f[0], b0, acc2, 0, 0, 0);
        acc2 = __builtin_amdgcn_mfma_f32_16x16x32_bf16(w2f[1], b1, acc2, 0, 0, 0);

        // ---- dice2 + W3: in-lane partial over 4 j's, then 2 shfl_xor over
        //      the qd4 groups -> every lane holds s for its own row rb+m
        float s = 0.f;
        #pragma unroll
        for (int reg = 0; reg < 4; ++reg) {
            const float x  = acc2[reg];
            const float xn = (x - m2p[reg]) * r2p[reg];
            const float p  = 1.f / (1.f + __expf(-xn));
            const float hd = x * (a2p[reg] + p * (1.f - a2p[reg]));
            s = fmaf(hd, w3p[reg], s);
        }
        s += __shfl_xor(s, 16);
        s += __shfl_xor(s, 32);
        const float w = (rb + m < nseq) ? 1.f / (1.f + __expf(-s)) : 0.f;

        // ---- phase 3: accumulate w * k-row from the registers we already
        //      hold (lane 16q+m owns row rb+m, cols q*8.. / 32+q*8..)
        #pragma unroll
        for (int jj = 0; jj < 4; ++jj) {
            oa0[jj] = fmaf(w, f0[jj], oa0[jj]);
            oa1[jj] = fmaf(w, f1[jj], oa1[jj]);
            oa2[jj] = fmaf(w, f2[jj], oa2[jj]);
            oa3[jj] = fmaf(w, f3[jj], oa3[jj]);
        }
    }

    // ---- once-per-kernel reduce over the 16 m-lanes of each q-group
    #pragma unroll
    for (int step = 1; step < 16; step <<= 1) {
        #pragma unroll
        for (int jj = 0; jj < 4; ++jj) {
            oa0[jj] += __shfl_xor(oa0[jj], step);
            oa1[jj] += __shfl_xor(oa1[jj], step);
            oa2[jj] += __shfl_xor(oa2[jj], step);
            oa3[jj] += __shfl_xor(oa3[jj], step);
        }
    }
    if (m == 0) {
        float* op = outp + wave * 64 + (qd4 << 3);
        *(fvec4*)(op)          = oa0;
        *(fvec4*)(op + 4)      = oa1;
        *(fvec4*)(op + 32)     = oa2;
        *(fvec4*)(op + 36)     = oa3;
    }
    __syncthreads();
    if (t < 64) {
        out[(size_t)b * DIM + t] = (outp[t] + outp[64 + t]) +
                                   (outp[128 + t] + outp[192 + t]);
    }
}

extern "C" void kernel_launch(void* const* d_in, const int* in_sizes, int n_in,
                              void* d_out, int out_size, void* d_ws, size_t ws_size,
                              hipStream_t stream) {
    const float* q      = (const float*)d_in[0];
    const float* key    = (const float*)d_in[1];
    const int*   seqlen = (const int*)d_in[2];
    const float* W1     = (const float*)d_in[3];
    const float* alpha1 = (const float*)d_in[4];
    const float* mean1  = (const float*)d_in[5];
    const float* var1   = (const float*)d_in[6];
    const float* W2     = (const float*)d_in[7];
    const float* alpha2 = (const float*)d_in[8];
    const float* mean2  = (const float*)d_in[9];
    const float* var2   = (const float*)d_in[10];
    const float* W3     = (const float*)d_in[11];
    float* out          = (float*)d_out;

    din_attn_kernel<<<NB, 256, 0, stream>>>(q, key, seqlen, W1,
                                            alpha1, mean1, var1,
                                            W2, alpha2, mean2, var2,
                                            W3, out);
}